// Round 11
// baseline (103.933 us; speedup 1.0000x reference)
//
#include <hip/hip_runtime.h>

#define N 8192
#define DIM 64

typedef float f32x4 __attribute__((ext_vector_type(4)));
typedef short bf16x8 __attribute__((ext_vector_type(8)));

__device__ __forceinline__ unsigned short f32_to_bf16_rne(float f) {
  unsigned int u = __float_as_uint(f);
  unsigned int r = (u + 0x7FFFu + ((u >> 16) & 1u)) >> 16;
  return (unsigned short)r;
}

// x (f32 [N][64]) -> xb (bf16 [N][64]); 131072 threads, 4 elems each
__global__ void cvt_kernel(const float* __restrict__ x, unsigned short* __restrict__ xb) {
  int gid = blockIdx.x * blockDim.x + threadIdx.x;
  float4 v = reinterpret_cast<const float4*>(x)[gid];
  ushort4 o;
  o.x = f32_to_bf16_rne(v.x);
  o.y = f32_to_bf16_rne(v.y);
  o.z = f32_to_bf16_rne(v.z);
  o.w = f32_to_bf16_rne(v.w);
  reinterpret_cast<ushort4*>(xb)[gid] = o;
}

// Grid: 512 blocks x 512 threads (8 waves). Block owns 16 rows x ALL 8192 j
// -> block-complete s_i, writes out directly (no spart, no finish kernel).
// XCD swizzle (T1): XCD x owns rows [x*1024, (x+1)*1024).
// Wave w: j in [w*1024, +1024), processed as 16 groups of 4 jt (64 j), with
// group-level double-buffer: per group 4 independent A float4 chains + 8 xj
// loads + 8 MFMA + 16 FMA == R9's proven inner mix (preserves MLP).
// Swapped-Gram: lane (q,c) of G-frag holds G[jt*16+q*4+v][i0+c].
// No device-scope fences/atomics (R7 lesson).
__global__ __launch_bounds__(512, 4) void main_kernel(
    const float* __restrict__ A,
    const unsigned short* __restrict__ xb,
    const float* __restrict__ x,
    float* __restrict__ out) {
  int bid = blockIdx.x;
  int xcd = bid & 7;
  int slot = bid >> 3;            // 0..63 within XCD
  int rg = xcd * 64 + slot;       // 16-row group; XCD-contiguous stripe
  int i0 = rg * 16;
  int tid = threadIdx.x;
  int w = tid >> 6;               // 0..7
  int lane = tid & 63;
  int c = lane & 15;              // G column (i); operand row selector
  int q = lane >> 4;              // k-quad; G row group (j)
  int jbase = w * 1024;

  // B-operand fragments (i-side), persistent: rows i0+c
  const unsigned short* pxi = xb + (size_t)(i0 + c) * DIM + q * 8;
  bf16x8 xi0 = *reinterpret_cast<const bf16x8*>(pxi);
  bf16x8 xi1 = *reinterpret_cast<const bf16x8*>(pxi + 32);

  // A row pointer: row i0+c, col jbase + q*4 (+ jt*16 added per step)
  const float* pA = A + (size_t)(i0 + c) * N + jbase + q * 4;
  // xj base: row jbase + c (+ jt*16 added per step)
  const unsigned short* pXJ = xb + (size_t)(jbase + c) * DIM + q * 8;

  float sacc = 0.f;

  f32x4 a_buf[2][4];
  bf16x8 xj_buf[2][4][2];

  // prologue: group 0 (jt = 0..3)
#pragma unroll
  for (int u = 0; u < 4; ++u) {
    a_buf[0][u] = *reinterpret_cast<const f32x4*>(pA + u * 16);
    const unsigned short* pj = pXJ + (size_t)(u * 16) * DIM;
    xj_buf[0][u][0] = *reinterpret_cast<const bf16x8*>(pj);
    xj_buf[0][u][1] = *reinterpret_cast<const bf16x8*>(pj + 32);
  }

#pragma unroll
  for (int jg = 0; jg < 16; ++jg) {
    const int cur = jg & 1, nxt = cur ^ 1;
    if (jg < 15) {
#pragma unroll
      for (int u = 0; u < 4; ++u) {
        int jt = (jg + 1) * 4 + u;
        a_buf[nxt][u] = *reinterpret_cast<const f32x4*>(pA + jt * 16);
        const unsigned short* pj = pXJ + (size_t)(jt * 16) * DIM;
        xj_buf[nxt][u][0] = *reinterpret_cast<const bf16x8*>(pj);
        xj_buf[nxt][u][1] = *reinterpret_cast<const bf16x8*>(pj + 32);
      }
    }
#pragma unroll
    for (int u = 0; u < 4; ++u) {
      f32x4 g = {0.f, 0.f, 0.f, 0.f};
      g = __builtin_amdgcn_mfma_f32_16x16x32_bf16(xj_buf[cur][u][0], xi0, g, 0, 0, 0);
      g = __builtin_amdgcn_mfma_f32_16x16x32_bf16(xj_buf[cur][u][1], xi1, g, 0, 0, 0);
      f32x4 a4 = a_buf[cur][u];
      sacc = fmaf(a4[0], g[0], sacc);
      sacc = fmaf(a4[1], g[1], sacc);
      sacc = fmaf(a4[2], g[2], sacc);
      sacc = fmaf(a4[3], g[3], sacc);
    }
  }

  // Sum over q within the wave: lanes c, c+16, c+32, c+48
  sacc += __shfl_xor(sacc, 16);
  sacc += __shfl_xor(sacc, 32);

  // Cross-wave reduce: red[w][c]
  __shared__ float red[8][16];
  if (lane < 16) red[w][lane] = sacc;
  __syncthreads();

  // Finish: threads 0..255 -> row r = t>>4, col quad (t&15)*4
  if (tid < 256) {
    int r = tid >> 4, cq = tid & 15;
    float s = 0.f;
#pragma unroll
    for (int ww = 0; ww < 8; ++ww) s += red[ww][r];  // fixed order, deterministic
    int i = i0 + r;
    f32x4 xv = *reinterpret_cast<const f32x4*>(x + (size_t)i * DIM + cq * 4);
    f32x4 o;
    o[0] = 1.0f - 0.1f * xv[0] - 0.01f * s;
    o[1] = 1.0f - 0.1f * xv[1] - 0.01f * s;
    o[2] = 1.0f - 0.1f * xv[2] - 0.01f * s;
    o[3] = 1.0f - 0.1f * xv[3] - 0.01f * s;
    *reinterpret_cast<f32x4*>(out + (size_t)i * DIM + cq * 4) = o;
  }
}

extern "C" void kernel_launch(void* const* d_in, const int* in_sizes, int n_in,
                              void* d_out, int out_size, void* d_ws, size_t ws_size,
                              hipStream_t stream) {
  // d_in[0] = t (unused), d_in[1] = x f32 [8192][64], d_in[2] = A f32 [8192][8192]
  const float* x = (const float*)d_in[1];
  const float* A = (const float*)d_in[2];
  float* out = (float*)d_out;

  unsigned short* xb = (unsigned short*)d_ws;  // 1 MB bf16 x

  cvt_kernel<<<512, 256, 0, stream>>>(x, xb);
  main_kernel<<<512, 512, 0, stream>>>(A, xb, x, out);
}

// Round 12
// 73.941 us; speedup vs baseline: 1.4056x; 1.4056x over previous
//
#include <hip/hip_runtime.h>

#define N 8192
#define DIM 64

typedef float f32x4 __attribute__((ext_vector_type(4)));
typedef short bf16x8 __attribute__((ext_vector_type(8)));

__device__ __forceinline__ unsigned short f32_to_bf16_rne(float f) {
  unsigned int u = __float_as_uint(f);
  unsigned int r = (u + 0x7FFFu + ((u >> 16) & 1u)) >> 16;
  return (unsigned short)r;
}

// x (f32 [N][64]) -> xb (bf16 [N][64]); 131072 threads, 4 elems each
__global__ void cvt_kernel(const float* __restrict__ x, unsigned short* __restrict__ xb) {
  int gid = blockIdx.x * blockDim.x + threadIdx.x;
  float4 v = reinterpret_cast<const float4*>(x)[gid];
  ushort4 o;
  o.x = f32_to_bf16_rne(v.x);
  o.y = f32_to_bf16_rne(v.y);
  o.z = f32_to_bf16_rne(v.z);
  o.w = f32_to_bf16_rne(v.w);
  reinterpret_cast<ushort4*>(xb)[gid] = o;
}

// Grid: 1024 blocks = 128 row-groups x 8 j-chunks, 256 threads (4 waves).
// XCD-aware swizzle (T1): XCD x (= bid%8) owns contiguous A row-stripe.
// Swapped-Gram: D[j'][i'] = mfma(xj_frag, xi_frag); lane (q,c) holds
// G[jt*16+q*4+v][i0+it*16+c] -> A loads are contiguous float4 along j.
// Proven best structure (74.2-74.3 us, reproduced): 16 waves/CU, 4 independent
// A-load chains per lane, compiler-scheduled (no explicit vmcnt/barriers).
// No device-scope fences/atomics (R7: agent fence = per-XCD L2 flush, -150us).
__global__ __launch_bounds__(256, 4) void main_kernel(
    const float* __restrict__ A,
    const unsigned short* __restrict__ xb,
    float* __restrict__ spart) {
  int bid = blockIdx.x;
  int xcd = bid & 7;
  int slot = bid >> 3;               // 0..127 within XCD
  int rg = xcd * 16 + (slot & 15);   // contiguous 16 row-groups per XCD
  int js = slot >> 4;                // 0..7
  int tid = threadIdx.x;
  int w = tid >> 6;
  int lane = tid & 63;
  int i0 = rg * 64;
  int jbase = js * 1024 + w * 256;
  int c = lane & 15;   // operand row/col selector, D column (i)
  int q = lane >> 4;   // k-quad; D row group (j)

  // B-operand fragments (i-side), persistent: B[k][col=c] = X[i0+it*16+c][k]
  bf16x8 xi[4][2];
#pragma unroll
  for (int it = 0; it < 4; ++it)
#pragma unroll
    for (int kb = 0; kb < 2; ++kb)
      xi[it][kb] = *reinterpret_cast<const bf16x8*>(
          xb + (size_t)(i0 + it * 16 + c) * DIM + kb * 32 + q * 8);

  // Per-it A row pointer: row i0+it*16+c, col jbase + q*4 (+ jt*16 folds to imm)
  const float* pA[4];
#pragma unroll
  for (int it = 0; it < 4; ++it)
    pA[it] = A + (size_t)(i0 + it * 16 + c) * N + jbase + q * 4;

  float sacc[4] = {0.f, 0.f, 0.f, 0.f};

  f32x4 a_buf[2][4];
  bf16x8 xj_buf[2][2];

  // prologue: jt=0 loads
#pragma unroll
  for (int it = 0; it < 4; ++it)
    a_buf[0][it] = *reinterpret_cast<const f32x4*>(pA[it]);
  {
    const unsigned short* pj = xb + (size_t)(jbase + c) * DIM + q * 8;
    xj_buf[0][0] = *reinterpret_cast<const bf16x8*>(pj);
    xj_buf[0][1] = *reinterpret_cast<const bf16x8*>(pj + 32);
  }

#pragma unroll
  for (int jt = 0; jt < 16; ++jt) {
    const int cur = jt & 1, nxt = cur ^ 1;
    if (jt < 15) {
#pragma unroll
      for (int it = 0; it < 4; ++it)
        a_buf[nxt][it] =
            *reinterpret_cast<const f32x4*>(pA[it] + (jt + 1) * 16);
      const unsigned short* pj =
          xb + (size_t)(jbase + (jt + 1) * 16 + c) * DIM + q * 8;
      xj_buf[nxt][0] = *reinterpret_cast<const bf16x8*>(pj);
      xj_buf[nxt][1] = *reinterpret_cast<const bf16x8*>(pj + 32);
    }
#pragma unroll
    for (int it = 0; it < 4; ++it) {
      f32x4 g = {0.f, 0.f, 0.f, 0.f};
      g = __builtin_amdgcn_mfma_f32_16x16x32_bf16(xj_buf[cur][0], xi[it][0], g, 0, 0, 0);
      g = __builtin_amdgcn_mfma_f32_16x16x32_bf16(xj_buf[cur][1], xi[it][1], g, 0, 0, 0);
      f32x4 a4 = a_buf[cur][it];
      sacc[it] = fmaf(a4[0], g[0], sacc[it]);
      sacc[it] = fmaf(a4[1], g[1], sacc[it]);
      sacc[it] = fmaf(a4[2], g[2], sacc[it]);
      sacc[it] = fmaf(a4[3], g[3], sacc[it]);
    }
  }

  // Sum over q (j sub-blocks within the wave): lanes c, c+16, c+32, c+48
#pragma unroll
  for (int it = 0; it < 4; ++it) {
    float s = sacc[it];
    s += __shfl_xor(s, 16);
    s += __shfl_xor(s, 32);
    sacc[it] = s;
  }

  __shared__ float red[4][64];
  if (q == 0) {
#pragma unroll
    for (int it = 0; it < 4; ++it)
      red[w][it * 16 + c] = sacc[it];
  }
  __syncthreads();
  if (tid < 64) {
    float s = red[0][tid] + red[1][tid] + red[2][tid] + red[3][tid];
    spart[(size_t)(i0 + tid) * 8 + js] = s;   // [i][js]: finish reads 32B runs
  }
}

// out[i][d] = 1 - 0.1*x[i][d] - 0.01*sum_js spart[i][js]; 131072 threads, 4 elems each
__global__ void finish_kernel(const float* __restrict__ x,
                              const float* __restrict__ spart,
                              float* __restrict__ out) {
  int gid = blockIdx.x * blockDim.x + threadIdx.x;
  float4 xv = reinterpret_cast<const float4*>(x)[gid];
  int i = gid >> 4;  // (gid*4)/64
  f32x4 p0 = *reinterpret_cast<const f32x4*>(spart + (size_t)i * 8);
  f32x4 p1 = *reinterpret_cast<const f32x4*>(spart + (size_t)i * 8 + 4);
  float s = ((p0[0] + p0[1]) + (p0[2] + p0[3])) + ((p1[0] + p1[1]) + (p1[2] + p1[3]));
  float4 o;
  o.x = 1.0f - 0.1f * xv.x - 0.01f * s;
  o.y = 1.0f - 0.1f * xv.y - 0.01f * s;
  o.z = 1.0f - 0.1f * xv.z - 0.01f * s;
  o.w = 1.0f - 0.1f * xv.w - 0.01f * s;
  reinterpret_cast<float4*>(out)[gid] = o;
}

extern "C" void kernel_launch(void* const* d_in, const int* in_sizes, int n_in,
                              void* d_out, int out_size, void* d_ws, size_t ws_size,
                              hipStream_t stream) {
  // d_in[0] = t (unused), d_in[1] = x f32 [8192][64], d_in[2] = A f32 [8192][8192]
  const float* x = (const float*)d_in[1];
  const float* A = (const float*)d_in[2];
  float* out = (float*)d_out;

  unsigned short* xb = (unsigned short*)d_ws;                  // 1 MB bf16 x
  float* spart = (float*)((char*)d_ws + (size_t)N * DIM * 2);  // 256 KB, [8192][8]

  cvt_kernel<<<512, 256, 0, stream>>>(x, xb);
  main_kernel<<<1024, 256, 0, stream>>>(A, xb, spart);
  finish_kernel<<<512, 256, 0, stream>>>(x, spart, out);
}